// Round 2
// baseline (726.376 us; speedup 1.0000x reference)
//
#include <hip/hip_runtime.h>
#include <math.h>

#define N_TOT  4096
#define C_DIM  64
#define P_DIM  512
#define SLOTS  (C_DIM * P_DIM)   // 32768 floats per sample
#define NC     4
#define NPAIRS 6
#define NCHUNK 64                // 2048 K2 blocks = 8/CU
#define NPER   (N_TOT / NCHUNK)  // 64 samples per chunk
#define K3_BLOCKS (SLOTS / 256)  // 128
#define PARTIAL_BYTES ((size_t)NCHUNK * NC * SLOTS * sizeof(float))  // 32 MiB

// native vector type: __builtin_nontemporal_load needs a scalar/native-vector
// pointee, not HIP's float4 class.
typedef float vf4 __attribute__((ext_vector_type(4)));

// ---------------------------------------------------------------------------
// K2: per-(n-chunk, class, slot) partial sums.  grid = (32, 64), block 256.
// 2048 blocks -> 8 blocks/CU -> 8 waves/SIMD (launch_bounds caps VGPR<=64).
// Each thread owns one float4 of the 32768-slot sample, streams NPER=64
// samples in 4-deep load batches.  Labels wave-uniform -> readfirstlane +
// scalar 0/1 masks, accumulate with fma(v, s_mask, acc); branch-free K-loop.
// x loads are nontemporal (zero reuse -> don't thrash L2; partial stays hot
// for K3).  Plain stores, single writer per element, no atomics.
// Block (0,0) thread 0 also resets the completion flag for the fused K3.
// ---------------------------------------------------------------------------
__global__ __launch_bounds__(256, 8)
void partial_sums_kernel(const float* __restrict__ x,
                         const int* __restrict__ labels,
                         float* __restrict__ partial,
                         unsigned int* __restrict__ flag) {
    __shared__ int lab[NPER];
    const int t     = threadIdx.x;
    const int chunk = blockIdx.y;
    const int n0    = chunk * NPER;

    if (t < NPER) lab[t] = labels[n0 + t];
    if (t == 0 && blockIdx.x == 0 && blockIdx.y == 0) *flag = 0u;
    __syncthreads();

    const int slot = blockIdx.x * 1024 + t * 4;
    vf4 a0 = (vf4)(0.0f);
    vf4 a1 = a0, a2 = a0, a3 = a0;

    const float* xp = x + (size_t)n0 * SLOTS + slot;
    for (int i = 0; i < NPER; i += 4) {
        vf4 v[4];
#pragma unroll
        for (int j = 0; j < 4; ++j)
            v[j] = __builtin_nontemporal_load(
                       (const vf4*)(xp + (size_t)j * SLOTS));
        xp += 4 * (size_t)SLOTS;
#pragma unroll
        for (int j = 0; j < 4; ++j) {
            const int l = __builtin_amdgcn_readfirstlane(lab[i + j]);
            const float m0 = (l == 0) ? 1.0f : 0.0f;
            const float m1 = (l == 1) ? 1.0f : 0.0f;
            const float m2 = (l == 2) ? 1.0f : 0.0f;
            const float m3 = (l == 3) ? 1.0f : 0.0f;
#pragma unroll
            for (int e = 0; e < 4; ++e) {
                a0[e] = fmaf(v[j][e], m0, a0[e]);
                a1[e] = fmaf(v[j][e], m1, a1[e]);
                a2[e] = fmaf(v[j][e], m2, a2[e]);
                a3[e] = fmaf(v[j][e], m3, a3[e]);
            }
        }
    }

    float* o = partial + ((size_t)chunk * NC) * SLOTS + slot;
    *(vf4*)(o)                     = a0;
    *(vf4*)(o + SLOTS)             = a1;
    *(vf4*)(o + 2 * (size_t)SLOTS) = a2;
    *(vf4*)(o + 3 * (size_t)SLOTS) = a3;
}

// ---------------------------------------------------------------------------
// K3 (+fused K4): per-block label histogram (L2-hit), reduce 64 chunk
// partials (4 independent accumulators per class to break the FP add chain),
// centers -> 6 pairwise squared-diff sums, block-reduce, store 6 floats.
// Then last-arriving block (device-scope ticket) reduces the 128x6 pair
// partials, sqrt, averages, writes the scalar -- K4 launch eliminated.
// grid = 128 blocks x 256 threads.
// ---------------------------------------------------------------------------
__global__ __launch_bounds__(256)
void pair_kernel(const float* __restrict__ partial,
                 const int* __restrict__ labels,
                 float* __restrict__ pairpart,
                 float* __restrict__ out,
                 unsigned int* __restrict__ flag) {
    const int t    = threadIdx.x;
    const int wave = t >> 6;
    const int lane = t & 63;

    // -- histogram of all 4096 labels, block-local --
    int cnt[NC] = {0, 0, 0, 0};
    for (int i = t; i < N_TOT; i += 256) {
        const int l = labels[i];
#pragma unroll
        for (int k = 0; k < NC; ++k) cnt[k] += (l == k) ? 1 : 0;
    }
    __shared__ int shc[4][NC];
#pragma unroll
    for (int k = 0; k < NC; ++k) {
        int v = cnt[k];
        for (int off = 32; off > 0; off >>= 1) v += __shfl_down(v, off, 64);
        if (lane == 0) shc[wave][k] = v;
    }
    __syncthreads();
    float inv[NC];
#pragma unroll
    for (int k = 0; k < NC; ++k) {
        const int c = shc[0][k] + shc[1][k] + shc[2][k] + shc[3][k];
        inv[k] = 1.0f / fmaxf((float)c, 1.0f);
    }

    // -- per-slot center values: 64-chunk reduce, ILP-4 --
    const int slot = blockIdx.x * 256 + t;
    float c[NC];
#pragma unroll
    for (int k = 0; k < NC; ++k) {
        const float* pk = partial + (size_t)k * SLOTS + slot;
        float s0 = 0.f, s1 = 0.f, s2 = 0.f, s3 = 0.f;
#pragma unroll
        for (int ch = 0; ch < NCHUNK; ch += 4) {
            s0 += pk[(size_t)(ch + 0) * NC * SLOTS];
            s1 += pk[(size_t)(ch + 1) * NC * SLOTS];
            s2 += pk[(size_t)(ch + 2) * NC * SLOTS];
            s3 += pk[(size_t)(ch + 3) * NC * SLOTS];
        }
        c[k] = ((s0 + s1) + (s2 + s3)) * inv[k];
    }

    // -- 6 pairwise squared diffs, block-reduced --
    float p[NPAIRS];
    {
        int pi = 0;
#pragma unroll
        for (int a_ = 0; a_ < NC; ++a_)
#pragma unroll
            for (int b_ = a_ + 1; b_ < NC; ++b_) {
                const float d = c[a_] - c[b_];
                p[pi++] = d * d;
            }
    }
    __shared__ float shp[4][NPAIRS];
#pragma unroll
    for (int i = 0; i < NPAIRS; ++i) {
        float v = p[i];
        for (int off = 32; off > 0; off >>= 1) v += __shfl_down(v, off, 64);
        if (lane == 0) shp[wave][i] = v;
    }
    __syncthreads();
    if (t < NPAIRS)
        pairpart[blockIdx.x * NPAIRS + t] =
            shp[0][t] + shp[1][t] + shp[2][t] + shp[3][t];

    // -- fused final reduce: last block to arrive does it --
    __threadfence();                       // pairpart visible device-wide
    __shared__ unsigned int ticket;
    if (t == 0) ticket = atomicAdd(flag, 1u);
    __syncthreads();
    if (ticket == K3_BLOCKS - 1) {
        __threadfence();                   // acquire side
        float q[NPAIRS];
#pragma unroll
        for (int i = 0; i < NPAIRS; ++i)
            q[i] = (t < K3_BLOCKS) ? pairpart[t * NPAIRS + i] : 0.0f;
        __syncthreads();                   // shp reuse
#pragma unroll
        for (int i = 0; i < NPAIRS; ++i) {
            float v = q[i];
            for (int off = 32; off > 0; off >>= 1) v += __shfl_down(v, off, 64);
            if (lane == 0) shp[wave][i] = v;
        }
        __syncthreads();
        if (t == 0) {
            float s = 0.0f;
#pragma unroll
            for (int i = 0; i < NPAIRS; ++i)
                s += sqrtf(shp[0][i] + shp[1][i] + shp[2][i] + shp[3][i]);
            out[0] = s * (1.0f / 6.0f);
        }
    }
}

// ---------------------------------------------------------------------------
extern "C" void kernel_launch(void* const* d_in, const int* in_sizes, int n_in,
                              void* d_out, int out_size, void* d_ws, size_t ws_size,
                              hipStream_t stream) {
    const float* x      = (const float*)d_in[0];
    const int*   labels = (const int*)d_in[1];
    float*       out    = (float*)d_out;

    // ws layout: partial[NCHUNK][NC][SLOTS] floats (32 MiB),
    // pairpart[K3_BLOCKS][NPAIRS] (3 KiB), then the ticket flag.
    float*        partial  = (float*)d_ws;
    float*        pairpart = (float*)((char*)d_ws + PARTIAL_BYTES);
    unsigned int* flag     = (unsigned int*)((char*)d_ws + PARTIAL_BYTES +
                                             (size_t)K3_BLOCKS * NPAIRS * sizeof(float));

    partial_sums_kernel<<<dim3(SLOTS / 1024, NCHUNK), 256, 0, stream>>>(
        x, labels, partial, flag);
    pair_kernel<<<K3_BLOCKS, 256, 0, stream>>>(
        partial, labels, pairpart, out, flag);
}